// Round 7
// baseline (339.024 us; speedup 1.0000x reference)
//
#include <hip/hip_runtime.h>

// 2D Haar DWT — LDS-repacked stores: one contiguous store stream per wave.
// x: (BC, 1024, 1024) fp32 -> out: [LL | LH | HL | HH], each (BC, 512, 512) fp32.
//   a=x[2i-1,2j-1] b=x[2i-1,2j] c=x[2i,2j-1] d=x[2i,2j]   (index -1 => 0)
//   LL=0.5(a+b+c+d) LH=0.5(c+d-a-b) HL=0.5((b-a)+(d-c)) HH=0.5((d-c)-(b-a))
//
// Block (256 thr) computes out tile: 4 rows x 512 cols of ALL subbands for one
// plane (input rows 8T-1..8T+6), staged in 32 KB LDS. Then wave w stores
// subband w: 4 consecutive output rows = 8 KB CONTIGUOUS per wave (vs 8
// scattered 1KB bursts/wave in all previous variants — the one structural
// difference vs the 6.6 TB/s fill kernel that previous rounds never tested).
// Compute phase = round-4's verified shfl-halo structure, unchanged.

typedef float fx4 __attribute__((ext_vector_type(4)));
typedef float fx2 __attribute__((ext_vector_type(2)));

__device__ __forceinline__ void haar_row(float hT, fx4 vT, float hB, fx4 vB,
                                         fx2& ll, fx2& lh, fx2& hl, fx2& hh)
{
    // out col 2jp:   a=hT,   b=vT.x, c=hB,   d=vB.x
    // out col 2jp+1: a=vT.y, b=vT.z, c=vB.y, d=vB.z
    float st0 = hT + vT.x,   dt0 = vT.x - hT;
    float sb0 = hB + vB.x,   db0 = vB.x - hB;
    float st1 = vT.y + vT.z, dt1 = vT.z - vT.y;
    float sb1 = vB.y + vB.z, db1 = vB.z - vB.y;
    ll = fx2{0.5f * (st0 + sb0), 0.5f * (st1 + sb1)};
    lh = fx2{0.5f * (sb0 - st0), 0.5f * (sb1 - st1)};
    hl = fx2{0.5f * (dt0 + db0), 0.5f * (dt1 + db1)};
    hh = fx2{0.5f * (db0 - dt0), 0.5f * (db1 - dt1)};
}

__global__ __launch_bounds__(256) void dwt_haar_kernel(
    const float* __restrict__ x, float* __restrict__ out, int n_bc)
{
    constexpr int W = 1024, Ho = 512, Wo = 512;
    const long long S = (long long)n_bc * Ho * Wo; // subband size (elements)

    // [subband][local_row 0..3][col 0..511]
    __shared__ float lds[4 * 4 * 512];             // 32 KB

    const int t  = threadIdx.x;
    const int bc = blockIdx.x >> 7;                // plane
    const int T  = blockIdx.x & 127;               // tile: out rows 4T..4T+3
    const int jp = t;                              // col-pair 0..255
    const int c0 = jp << 2;                        // input col 4*jp

    // ---- compute phase: two row-pairs (k=0,1), round-4 structure ----
#pragma unroll
    for (int k = 0; k < 2; ++k) {
        const int i2 = 2 * T + k;                  // row-pair: out rows 2i2,2i2+1
        const float* rB = x + ((long long)bc << 20) + (long long)(i2 << 2) * W + c0;
        const bool have_top = (i2 != 0);           // block-uniform

        fx4 vB = *(const fx4*)(rB);                // row 4*i2
        fx4 vC = *(const fx4*)(rB + W);            // row 4*i2+1
        fx4 vD = *(const fx4*)(rB + 2 * W);        // row 4*i2+2
        fx4 vA = fx4{0.f, 0.f, 0.f, 0.f};          // row 4*i2-1
        if (have_top) vA = *(const fx4*)(rB - W);

        float hA = __shfl_up(vA.w, 1);
        float hB = __shfl_up(vB.w, 1);
        float hC = __shfl_up(vC.w, 1);
        float hD = __shfl_up(vD.w, 1);
        if ((t & 63) == 0) {                       // wave lane 0
            if (jp == 0) {
                hA = hB = hC = hD = 0.f;           // left zero-pad
            } else {                               // L1/L2-hit patch loads
                hB = rB[-1];
                hC = rB[W - 1];
                hD = rB[2 * W - 1];
                hA = have_top ? rB[-W - 1] : 0.f;
            }
        }

        fx2 ll0, lh0, hl0, hh0, ll1, lh1, hl1, hh1;
        haar_row(hA, vA, hB, vB, ll0, lh0, hl0, hh0); // out row 2*i2
        haar_row(hC, vC, hD, vD, ll1, lh1, hl1, hh1); // out row 2*i2+1

        const int r0 = 2 * k, r1 = 2 * k + 1;      // local rows in tile
        const int cc = jp << 1;                    // out col 2*jp
        *(fx2*)&lds[(0 * 4 + r0) * 512 + cc] = ll0;
        *(fx2*)&lds[(1 * 4 + r0) * 512 + cc] = lh0;
        *(fx2*)&lds[(2 * 4 + r0) * 512 + cc] = hl0;
        *(fx2*)&lds[(3 * 4 + r0) * 512 + cc] = hh0;
        *(fx2*)&lds[(0 * 4 + r1) * 512 + cc] = ll1;
        *(fx2*)&lds[(1 * 4 + r1) * 512 + cc] = lh1;
        *(fx2*)&lds[(2 * 4 + r1) * 512 + cc] = hl1;
        *(fx2*)&lds[(3 * 4 + r1) * 512 + cc] = hh1;
    }

    __syncthreads();

    // ---- store phase: wave w stores subband w, 4 rows = 8 KB contiguous ----
    const int w = t >> 6, l = t & 63;
    float* obase = out + (long long)w * S
                 + ((long long)bc * Ho + 4 * T) * Wo;
#pragma unroll
    for (int lr = 0; lr < 4; ++lr) {
        const float* src = &lds[(w * 4 + lr) * 512];
        fx4 a = *(const fx4*)(src + 4 * l);        // canonical conflict-free b128
        fx4 b = *(const fx4*)(src + 4 * l + 256);
        *(fx4*)(obase + lr * Wo + 4 * l)       = a; // cols 0..255   (1KB/instr)
        *(fx4*)(obase + lr * Wo + 4 * l + 256) = b; // cols 256..511 (1KB/instr)
    }
}

extern "C" void kernel_launch(void* const* d_in, const int* in_sizes, int n_in,
                              void* d_out, int out_size, void* d_ws, size_t ws_size,
                              hipStream_t stream) {
    const float* x = (const float*)d_in[0];
    float* out = (float*)d_out;

    const int n_bc = in_sizes[0] / (1024 * 1024);  // B*C = 48
    const int blocks = n_bc * 128;                 // 128 tiles/plane -> 6144
    dwt_haar_kernel<<<blocks, 256, 0, stream>>>(x, out, n_bc);
}

// Round 8
// 331.783 us; speedup vs baseline: 1.0218x; 1.0218x over previous
//
#include <hip/hip_runtime.h>

// 2D Haar DWT, single fused pass, 2 output rows per thread. (Champion, R6.)
// x: (BC, 1024, 1024) fp32 -> out: [LL | LH | HL | HH], each (BC, 512, 512) fp32.
// Per output pixel (i,j):
//   a=x[2i-1,2j-1] b=x[2i-1,2j] c=x[2i,2j-1] d=x[2i,2j]   (index -1 => 0)
//   LL=0.5(a+b+c+d) LH=0.5(c+d-a-b) HL=0.5((b-a)+(d-c)) HH=0.5((d-c)-(b-a))
// Verified A/B results on this problem:
//   - NT stores cost +12 us (force write-drain into dispatch window) -> plain.
//   - LDS store-repack costs +7 us (barrier + round-trip) -> direct stores.
//   - coalescing width / MLP / pipelining: all neutral (memory regime is the
//     limiter at channel level, not lane level).

typedef float fx4 __attribute__((ext_vector_type(4)));

__device__ __forceinline__ void haar_pair(const float t[9], const float b[9],
                                          fx4& ll, fx4& lh, fx4& hl, fx4& hh)
{
#pragma unroll
    for (int k = 0; k < 4; ++k) {
        float a = t[2 * k], bb = t[2 * k + 1];
        float c = b[2 * k], d  = b[2 * k + 1];
        float sum_t = a + bb, dif_t = bb - a;
        float sum_b = c + d,  dif_b = d - c;
        ll[k] = 0.5f * (sum_t + sum_b);
        lh[k] = 0.5f * (sum_b - sum_t);
        hl[k] = 0.5f * (dif_t + dif_b);
        hh[k] = 0.5f * (dif_b - dif_t);
    }
}

__global__ __launch_bounds__(256) void dwt_haar_kernel(
    const float* __restrict__ x, float* __restrict__ out, int n_bc)
{
    constexpr int W  = 1024;   // input width
    constexpr int Ho = 512;    // output height
    constexpr int Wo = 512;    // output width

    const long long S = (long long)n_bc * Ho * Wo; // subband size (elements)

    int g   = blockIdx.x * 256 + threadIdx.x;
    int j4  = g & 127;             // col group within row (128 per row)
    int rem = g >> 7;
    int i2  = rem & 255;           // row-pair index: out rows 2*i2, 2*i2+1
    int bc  = rem >> 8;            // image plane

    const int c0 = j4 << 3;        // input col 8*j4
    // input row 4*i2 (bottom row of first output row), at col c0
    const float* r1 = x + ((long long)bc * 1024 + 4 * i2) * W + c0;

    // ---- issue all vector loads up-front (independent, max MLP) ----
    float4 v1a = *(const float4*)(r1);
    float4 v1b = *(const float4*)(r1 + 4);
    float4 v2a = *(const float4*)(r1 + W);
    float4 v2b = *(const float4*)(r1 + W + 4);
    float4 v3a = *(const float4*)(r1 + 2 * W);
    float4 v3b = *(const float4*)(r1 + 2 * W + 4);
    float4 v0a, v0b;
    const bool have_top = (i2 > 0);      // wave-uniform
    if (have_top) {                      // input row 4*i2-1
        v0a = *(const float4*)(r1 - W);
        v0b = *(const float4*)(r1 - W + 4);
    } else {
        v0a = make_float4(0.f, 0.f, 0.f, 0.f);
        v0b = v0a;
    }

    // halo col 8*j4-1 for each of the 4 input rows (L1 hits; zero-pad at -1)
    float h0 = 0.f, h1 = 0.f, h2 = 0.f, h3 = 0.f;
    if (j4 > 0) {
        h1 = r1[-1];
        h2 = r1[W - 1];
        h3 = r1[2 * W - 1];
        if (have_top) h0 = r1[-W - 1];
    }

    // ---- assemble 9-wide windows ----
    float w0[9], w1[9], w2[9], w3[9];
    w0[0] = h0; w0[1] = v0a.x; w0[2] = v0a.y; w0[3] = v0a.z; w0[4] = v0a.w;
                w0[5] = v0b.x; w0[6] = v0b.y; w0[7] = v0b.z; w0[8] = v0b.w;
    w1[0] = h1; w1[1] = v1a.x; w1[2] = v1a.y; w1[3] = v1a.z; w1[4] = v1a.w;
                w1[5] = v1b.x; w1[6] = v1b.y; w1[7] = v1b.z; w1[8] = v1b.w;
    w2[0] = h2; w2[1] = v2a.x; w2[2] = v2a.y; w2[3] = v2a.z; w2[4] = v2a.w;
                w2[5] = v2b.x; w2[6] = v2b.y; w2[7] = v2b.z; w2[8] = v2b.w;
    w3[0] = h3; w3[1] = v3a.x; w3[2] = v3a.y; w3[3] = v3a.z; w3[4] = v3a.w;
                w3[5] = v3b.x; w3[6] = v3b.y; w3[7] = v3b.z; w3[8] = v3b.w;

    // ---- compute both output rows ----
    fx4 ll0, lh0, hl0, hh0, ll1, lh1, hl1, hh1;
    haar_pair(w0, w1, ll0, lh0, hl0, hh0);   // out row 2*i2   (top=4i2-1, bot=4i2)
    haar_pair(w2, w3, ll1, lh1, hl1, hh1);   // out row 2*i2+1 (top=4i2+1, bot=4i2+2)

    // ---- PLAIN float4 stores (L2/L3 write-back absorbs; flush after kernel) ----
    const long long obase0 = ((long long)bc * Ho + 2 * i2) * Wo + (j4 << 2);
    const long long obase1 = obase0 + Wo;

    *(fx4*)(out +         obase0) = ll0;
    *(fx4*)(out +     S + obase0) = lh0;
    *(fx4*)(out + 2 * S + obase0) = hl0;
    *(fx4*)(out + 3 * S + obase0) = hh0;
    *(fx4*)(out +         obase1) = ll1;
    *(fx4*)(out +     S + obase1) = lh1;
    *(fx4*)(out + 2 * S + obase1) = hl1;
    *(fx4*)(out + 3 * S + obase1) = hh1;
}

extern "C" void kernel_launch(void* const* d_in, const int* in_sizes, int n_in,
                              void* d_out, int out_size, void* d_ws, size_t ws_size,
                              hipStream_t stream) {
    const float* x = (const float*)d_in[0];
    float* out = (float*)d_out;

    const int n_bc = in_sizes[0] / (1024 * 1024);              // B*C = 48
    // one thread per (plane, row-pair, col-group): 48 * 256 * 128
    const long long total_threads = (long long)n_bc * 256 * 128;
    const int blocks = (int)(total_threads / 256);             // 6144

    dwt_haar_kernel<<<blocks, 256, 0, stream>>>(x, out, n_bc);
}